// Round 1
// baseline (249.830 us; speedup 1.0000x reference)
//
#include <hip/hip_runtime.h>

// MyLSTM: 2-layer LSTM (input=3, hidden=4) + MLP head (4->4 tanh -> 1), B=4096, T=1024.
//
// R9 = R8 (170 us kernel, VALUBusy 81%, 2 waves/SIMD) with the MLP head EXTRACTED from
// stage B into a third wave type C. Rationale: per-SIMD issue demand was A~78 + B~126
// cyc/step; the head inside B cost ~46 cyc/step, computed with 16-lane redundancy and a
// per-step cmp/cndmask select, despite being pure feed-forward (not in the recurrence).
// C consumes h1 via a second credit ring and processes 4 timesteps per iteration with
// zero lane redundancy (lane = chain*16 + stepsub*4 + unit): ~11 cyc/step instead of 46.
// New per-SIMD demand: A 78 + B 80 + C ~12 = ~170 cyc/step (-17%), and 3 waves/SIMD
// (12 waves, w%4 round-robin puts one A, one B, one C of the SAME pair on each SIMD)
// fill the trans-latency bubbles that capped VALUBusy at 81%.
//
// Cell math of BOTH LSTM layers is byte-identical to R8 (recurrent trajectories, hence
// absmax = 0.001953125, unchanged). Head dot products are reassociated (plain order);
// ~1-ulp effect on y only, far below the 2^-9 activation-approx error.
// Ring-1 protocol is a verbatim copy of the proven ring-0 pattern: monotonic chunk
// counters, __threadfence_block before done-flags, per-wave in-order LDS pipeline for
// the free-flag release, s_sleep polling (a polling wave issues ~nothing).

#define T_STEPS 1024
#define BATCH   4096
#define CHUNK   16
#define NCHUNK  (T_STEPS / CHUNK)
#define RDEPTH  4   // ring depth in chunks (power of 2)

__device__ __forceinline__ float fast_exp2(float x) {
#if __has_builtin(__builtin_amdgcn_exp2f)
    return __builtin_amdgcn_exp2f(x);
#else
    return exp2f(x);
#endif
}

__device__ __forceinline__ float fast_rcp(float x) {
#if __has_builtin(__builtin_amdgcn_rcpf)
    return __builtin_amdgcn_rcpf(x);
#else
    return 1.0f / x;
#endif
}

// tanh(x) = 2*sigmoid(2x) - 1 = 2/(1+exp2(-2.885390x)) - 1
__device__ __forceinline__ float fast_tanh(float x) {
    return 2.0f * fast_rcp(1.0f + fast_exp2(-2.88539008f * x)) - 1.0f;
}

template <int CTRL>
__device__ __forceinline__ float dpp_mov(float v) {
    int i = __builtin_bit_cast(int, v);
    i = __builtin_amdgcn_mov_dpp(i, CTRL, 0xF, 0xF, true);
    return __builtin_bit_cast(float, i);
}

#define DPP_QB0         0x00   // quad_perm [0,0,0,0] -> i gate
#define DPP_QB1         0x55   // quad_perm [1,1,1,1] -> f gate
#define DPP_QB2         0xAA   // quad_perm [2,2,2,2] -> g gate
#define DPP_QB3         0xFF   // quad_perm [3,3,3,3] -> o gate
#define DPP_ROR8        0x128  // l^8  -> u^2 (on quad-uniform data)
#define DPP_MIRROR      0x140  // l^15 -> u^3 (on quad-uniform data)
#define DPP_HALF_MIRROR 0x141  // l^7  -> u^1 (on quad-uniform data)
#define DPP_QSWAP2      0x4E   // quad_perm [2,3,0,1] -> u^2 within quad
#define DPP_QSWAP1      0xB1   // quad_perm [1,0,3,2] -> u^1 within quad

__global__ __launch_bounds__(768) void lstm_r9_kernel(
    const float* __restrict__ x,
    const float* __restrict__ W_ih0, const float* __restrict__ W_hh0,
    const float* __restrict__ b_ih0, const float* __restrict__ b_hh0,
    const float* __restrict__ W_ih1, const float* __restrict__ W_hh1,
    const float* __restrict__ b_ih1, const float* __restrict__ b_hh1,
    const float* __restrict__ W1, const float* __restrict__ b1,
    const float* __restrict__ W2, const float* __restrict__ b2,
    float* __restrict__ out)
{
    // x stage: [pair][slot][ch*17 + step] (A-private, self-ordered; +17 pad)
    __shared__ float4 xstage[4][2][68];
    // h0 ring A->B: [pair][slot][step][chain], plain-order h[4] per chain (16 KB)
    __shared__ float4 ring0[4][RDEPTH][CHUNK][4];
    // h1 ring B->C: same layout (16 KB)
    __shared__ float4 ring1[4][RDEPTH][CHUNK][4];
    // monotonic chunk counters (value c+1 = chunk c produced / freed)
    __shared__ int done0[4][RDEPTH];
    __shared__ int free0[4][RDEPTH];
    __shared__ int done1[4][RDEPTH];
    __shared__ int free1[4][RDEPTH];

    const int tid  = threadIdx.x;
    const int wave = tid >> 6;
    const int stg  = wave >> 2;         // 0 = L0 producer, 1 = L1 mid, 2 = head consumer
    const int pr   = wave & 3;          // pair index: A/B/C waves with same pr share rings
    const int lane = tid & 63;
    const int idx  = lane & 15;         // lane within 16-lane chain group (also step-slot)
    const int rho  = lane & 3;          // role: 0=i,1=f,2=g,3=o
    const int u    = (lane >> 2) & 3;   // hidden unit
    const int r    = rho * 4 + u;       // gate row in 16-row weight matrices
    const int ch   = lane >> 4;         // chain within pair
    const int batch = blockIdx.x * 16 + pr * 4 + ch;

    // init flags, one barrier total (outside hot loop)
    if (tid < 4 * RDEPTH) {
        done0[tid >> 2][tid & 3] = 0;
        free0[tid >> 2][tid & 3] = 0;
        done1[tid >> 2][tid & 3] = 0;
        free1[tid >> 2][tid & 3] = 0;
    }
    __syncthreads();

    // Per-lane activation constants: role g (rho==2) uses tanh = 2*sigma(2x)-1.
    const float am = (rho == 2) ? -2.88539008f : -1.44269504f;
    const float aa = (rho == 2) ? 2.0f : 1.0f;
    const float ab = (rho == 2) ? -1.0f : 0.0f;

    if (stg == 0) {
        // ======================= stage A: layer 0 producer =======================
        const float wx0 = W_ih0[r * 3 + 0];
        const float wx1 = W_ih0[r * 3 + 1];
        const float wx2 = W_ih0[r * 3 + 2];
        const float bias0 = b_ih0[r] + b_hh0[r];
        float wh0[4];
#pragma unroll
        for (int k = 0; k < 4; ++k) wh0[k] = W_hh0[r * 4 + (u ^ k)];   // xor order

        float h0 = 0.f, c0 = 0.f, h0b = 0.f, h0c = 0.f, h0d = 0.f;

        const float* xrow = x + (size_t)batch * T_STEPS * 3;
        // prime: stage chunk 0 into x-slot 0, load chunk 1 into regs
        const float* p0 = xrow + idx * 3;
        xstage[pr][0][ch * 17 + idx] = make_float4(p0[0], p0[1], p0[2], 0.f);
        const float* p1 = xrow + 48 + idx * 3;
        float q0 = p1[0], q1 = p1[1], q2 = p1[2];

        volatile int* ff = &free0[pr][0];

        for (int c = 0; c < NCHUNK; ++c) {
            const int s = c & (RDEPTH - 1);
            // ring credit: previous occupant of slot s was chunk c-RDEPTH
            if (c >= RDEPTH) {
                while (ff[s] < c - RDEPTH + 1) { __builtin_amdgcn_s_sleep(1); }
            }

            const float4* xs = &xstage[pr][c & 1][ch * 17];
            float4 xc = xs[0];
#pragma unroll
            for (int tt = 0; tt < CHUNK; ++tt) {
                float4 xn = xs[(tt < CHUNK - 1) ? tt + 1 : tt];   // 1-step LDS prefetch

                float pre0 = bias0 + wx0 * xc.x + wx1 * xc.y + wx2 * xc.z
                           + wh0[0] * h0 + wh0[1] * h0b + wh0[2] * h0c + wh0[3] * h0d;
                float a0 = aa * fast_rcp(1.0f + fast_exp2(am * pre0)) + ab;
                float gi = dpp_mov<DPP_QB0>(a0);
                float gf = dpp_mov<DPP_QB1>(a0);
                float gg = dpp_mov<DPP_QB2>(a0);
                float go = dpp_mov<DPP_QB3>(a0);
                c0 = gf * c0 + gi * gg;
                h0 = go * fast_tanh(c0);
                h0b = dpp_mov<DPP_HALF_MIRROR>(h0);
                h0c = dpp_mov<DPP_ROR8>(h0);
                h0d = dpp_mov<DPP_MIRROR>(h0);

                if (rho == 0) ((float*)&ring0[pr][s][tt][ch])[u] = h0;  // plain h0[u]
                xc = xn;
            }
            // publish chunk c
            __threadfence_block();
            if (lane == 0) done0[pr][s] = c + 1;

            // stage chunk c+1 (regs loaded last chunk), prefetch chunk c+2
            if (c < NCHUNK - 1)
                xstage[pr][(c + 1) & 1][ch * 17 + idx] = make_float4(q0, q1, q2, 0.f);
            if (c < NCHUNK - 2) {
                const float* p = xrow + (c + 2) * 48 + idx * 3;
                q0 = p[0]; q1 = p[1]; q2 = p[2];
            }
        }
    } else if (stg == 1) {
        // ==================== stage B: layer 1 (cell only) =======================
        const float bias1 = b_ih1[r] + b_hh1[r];
        float wi1[4], wh1[4];
#pragma unroll
        for (int k = 0; k < 4; ++k) {
            wi1[k] = W_ih1[r * 4 + k];          // PLAIN order (ring h0 is plain)
            wh1[k] = W_hh1[r * 4 + (u ^ k)];    // xor order (register quad)
        }

        float h1 = 0.f, c1 = 0.f, h1b = 0.f, h1c = 0.f, h1d = 0.f;

        volatile int* df = &done0[pr][0];
        volatile int* f1 = &free1[pr][0];

        for (int c = 0; c < NCHUNK; ++c) {
            const int s = c & (RDEPTH - 1);
            while (df[s] < c + 1) { __builtin_amdgcn_s_sleep(1); }
            if (c >= RDEPTH) {
                while (f1[s] < c - RDEPTH + 1) { __builtin_amdgcn_s_sleep(1); }
            }
            __threadfence_block();

            const float4* rgp = &ring0[pr][s][0][ch];   // step stride = 4 float4s
            float4 h_a = rgp[0];
            float4 h_b = rgp[4];
#pragma unroll
            for (int tt = 0; tt < CHUNK; ++tt) {
                // 2-step LDS prefetch (clamped; dead value near chunk end)
                float4 h_n = rgp[4 * ((tt < CHUNK - 2) ? tt + 2 : CHUNK - 1)];

                float pre1 = bias1
                           + wi1[0] * h_a.x + wi1[1] * h_a.y
                           + wi1[2] * h_a.z + wi1[3] * h_a.w
                           + wh1[0] * h1 + wh1[1] * h1b + wh1[2] * h1c + wh1[3] * h1d;
                float a1 = aa * fast_rcp(1.0f + fast_exp2(am * pre1)) + ab;
                float gi1 = dpp_mov<DPP_QB0>(a1);
                float gf1 = dpp_mov<DPP_QB1>(a1);
                float gg1 = dpp_mov<DPP_QB2>(a1);
                float go1 = dpp_mov<DPP_QB3>(a1);
                c1 = gf1 * c1 + gi1 * gg1;
                h1 = go1 * fast_tanh(c1);
                h1b = dpp_mov<DPP_HALF_MIRROR>(h1);
                h1c = dpp_mov<DPP_ROR8>(h1);
                h1d = dpp_mov<DPP_MIRROR>(h1);

                if (rho == 0) ((float*)&ring1[pr][s][tt][ch])[u] = h1;  // plain h1[u]

                h_a = h_b; h_b = h_n;
            }
            // release ring0 slot (reads all consumed; per-wave LDS is in-order),
            // then publish ring1 chunk (fence makes data visible before flag)
            if (lane == 0) free0[pr][s] = c + 1;
            __threadfence_block();
            if (lane == 0) done1[pr][s] = c + 1;
        }
    } else {
        // =================== stage C: MLP head consumer ==========================
        // Zero-redundancy layout: lane = cch*16 + sb*4 + cu handles (chain cch,
        // step it*4+sb, unit cu) -> 4 timesteps per iteration across 64 lanes.
        const int cu  = lane & 3;           // hidden unit
        const int sb  = (lane >> 2) & 3;    // step sub-slot
        const int cch = lane >> 4;          // chain within pair
        const int cbatch = blockIdx.x * 16 + pr * 4 + cch;

        float w1r[4];
#pragma unroll
        for (int k = 0; k < 4; ++k) w1r[k] = W1[cu * 4 + k];   // plain order
        const float b1u = b1[cu];
        const float w2u = W2[cu];
        const float b2v = b2[0];
        float* op = out + (size_t)cbatch * T_STEPS;

        volatile int* d1 = &done1[pr][0];

        for (int c = 0; c < NCHUNK; ++c) {
            const int s = c & (RDEPTH - 1);
            while (d1[s] < c + 1) { __builtin_amdgcn_s_sleep(1); }
            __threadfence_block();

            // lane reads h1[chain cch][t = it*4+sb] as one float4 (quad-broadcast,
            // 2-way bank aliasing = free); it*16 float4s = it*256 B imm offset
            const float4* rg = &ring1[pr][s][sb][cch];
            float yq[4];
#pragma unroll
            for (int it = 0; it < 4; ++it) {
                float4 h = rg[it * 16];
                float zp = b1u + w1r[0] * h.x + w1r[1] * h.y
                               + w1r[2] * h.z + w1r[3] * h.w;
                float z  = fast_tanh(zp);
                float yv = w2u * z;
                // sum over the 4 units of the quad: (u + u^2) + (u^1 + u^3) + b2
                float t1 = yv + dpp_mov<DPP_QSWAP2>(yv);
                yq[it]   = t1 + dpp_mov<DPP_QSWAP1>(t1) + b2v;
            }
            // release ring1 slot (all reads consumed above; values live in yq regs)
            if (lane == 0) free1[pr][s] = c + 1;

            // store: 16 active lanes (cch, sb), 4 consecutive floats per chain per it
            if (cu == 0) {
#pragma unroll
                for (int it = 0; it < 4; ++it)
                    op[c * CHUNK + it * 4 + sb] = yq[it];
            }
        }
    }
}

extern "C" void kernel_launch(void* const* d_in, const int* in_sizes, int n_in,
                              void* d_out, int out_size, void* d_ws, size_t ws_size,
                              hipStream_t stream) {
    const float* x     = (const float*)d_in[0];
    const float* W_ih0 = (const float*)d_in[1];
    const float* W_hh0 = (const float*)d_in[2];
    const float* b_ih0 = (const float*)d_in[3];
    const float* b_hh0 = (const float*)d_in[4];
    const float* W_ih1 = (const float*)d_in[5];
    const float* W_hh1 = (const float*)d_in[6];
    const float* b_ih1 = (const float*)d_in[7];
    const float* b_hh1 = (const float*)d_in[8];
    const float* W1    = (const float*)d_in[9];
    const float* b1    = (const float*)d_in[10];
    const float* W2    = (const float*)d_in[11];
    const float* b2    = (const float*)d_in[12];
    float* out = (float*)d_out;

    dim3 grid(BATCH / 16);   // 256 blocks = 1 per CU, 16 chains each
    dim3 block(768);         // 12 waves: 4x A (L0) + 4x B (L1) + 4x C (head);
                             // w%4 round-robin -> each SIMD gets one A, one B, one C
    lstm_r9_kernel<<<grid, block, 0, stream>>>(
        x, W_ih0, W_hh0, b_ih0, b_hh0, W_ih1, W_hh1, b_ih1, b_hh1,
        W1, b1, W2, b2, out);
}